// Round 2
// baseline (1715.960 us; speedup 1.0000x reference)
//
#include <hip/hip_runtime.h>
#include <hip/hip_bf16.h>

typedef __attribute__((ext_vector_type(8))) short short8;
typedef __attribute__((ext_vector_type(4))) float floatx4;

__device__ __forceinline__ float bits2f(unsigned short u) {
    union { unsigned int i; float f; } v; v.i = ((unsigned int)u) << 16; return v.f;
}
__device__ __forceinline__ unsigned short f2bb(float x) {  // RNE f32->bf16 bits
    union { float f; unsigned int i; } v; v.f = x;
    unsigned int r = v.i + 0x7FFFu + ((v.i >> 16) & 1u);
    return (unsigned short)(r >> 16);
}
// dtype-agnostic scalar load (fp32 flag is wave-uniform)
__device__ __forceinline__ float ldf(const void* base, long i, int fp32) {
    return fp32 ? ((const float*)base)[i] : bits2f(((const unsigned short*)base)[i]);
}
// dtype-agnostic 8-element row fragment load -> bf16 bits
__device__ __forceinline__ short8 loadRow8(const void* base, long off, int fp32) {
    short8 r;
    if (!fp32) {
        r = *(const short8*)((const unsigned short*)base + off);
    } else {
        const float* f = (const float*)base + off;
        #pragma unroll
        for (int j = 0; j < 8; ++j) r[j] = (short)f2bb(f[j]);
    }
    return r;
}
__device__ __forceinline__ float lclamp(float z) {  // NaN-laundering clamp
    return fminf(fmaxf(z, -1e4f), 1e4f);
}

// ---------------------------------------------------------------------------
// Probe: decide if float tensors are fp32 or bf16. For bf16 data, even-index
// u16s are bf16 values with exponent near 127; for fp32 data they are low
// mantissa bits (uniform exponent field).
// ---------------------------------------------------------------------------
__global__ void k_probe(const unsigned short* __restrict__ Wb, int* __restrict__ flag) {
    int t = threadIdx.x;                 // 64 threads
    unsigned short u = Wb[t * 2];        // even-indexed u16
    unsigned e = (u >> 7) & 0xFF;        // bf16 exponent field
    int in = (e >= 0x60 && e <= 0x8F) ? 1 : 0;
    unsigned long long m = __ballot(in);
    if (t == 0) flag[0] = (__popcll(m) < 32) ? 1 : 0;   // 1 => fp32
}

// ---------------------------------------------------------------------------
// K1: per-atom projection.  P[a][0:128] = atom[a]@W[0:64,:] + b  (bf16)
//                           P[a][128:256] = atom[a]@W[64:128,:]
// ---------------------------------------------------------------------------
__global__ __launch_bounds__(256) void k_atom_proj(
    const void* __restrict__ atom,
    const void* __restrict__ Wv,         // [192][128]
    const void* __restrict__ bv,         // [128]
    __hip_bfloat16* __restrict__ P, int N, const int* __restrict__ flagp)
{
    const int fp32 = *flagp;
    const int t = threadIdx.x;
    const int wave = t >> 6, lane = t & 63;
    const int half = wave & 1;
    const int pairInBlk = wave >> 1;
    const int n0 = lane & 15, kq = lane >> 4;

    short8 bf[8][2];
    #pragma unroll
    for (int tt = 0; tt < 8; ++tt)
        #pragma unroll
        for (int h = 0; h < 2; ++h)
            #pragma unroll
            for (int jj = 0; jj < 8; ++jj) {
                int k = half*64 + h*32 + kq*8 + jj;
                bf[tt][h][jj] = (short)f2bb(ldf(Wv, (long)k*128 + tt*16 + n0, fp32));
            }
    float bias[8];
    #pragma unroll
    for (int tt = 0; tt < 8; ++tt)
        bias[tt] = half ? 0.f : ldf(bv, tt*16 + n0, fp32);

    const long nGroups = ((long)N + 15) / 16;
    for (long g = (long)blockIdx.x*2 + pairInBlk; g < nGroups; g += (long)gridDim.x*2) {
        long a0 = g * 16;
        long am = a0 + n0;
        short8 a_lo = {}, a_hi = {};
        if (am < N) {
            a_lo = loadRow8(atom, am*64 + kq*8, fp32);
            a_hi = loadRow8(atom, am*64 + 32 + kq*8, fp32);
        }
        #pragma unroll
        for (int tt = 0; tt < 8; ++tt) {
            floatx4 c = {0.f, 0.f, 0.f, 0.f};
            c = __builtin_amdgcn_mfma_f32_16x16x32_bf16(a_lo, bf[tt][0], c, 0, 0, 0);
            c = __builtin_amdgcn_mfma_f32_16x16x32_bf16(a_hi, bf[tt][1], c, 0, 0, 0);
            #pragma unroll
            for (int r = 0; r < 4; ++r) {
                long a = a0 + kq*4 + r;
                if (a < N)
                    P[a*256 + half*128 + tt*16 + n0] =
                        __float2bfloat16(lclamp(c[r] + bias[tt]));
            }
        }
    }
}

// ---------------------------------------------------------------------------
// K2/K4: edge pass. z_e[n] = (nbr_e @ W3)[n] + P1[src_e][n] + P2[dst_e][n]
// PHASE 0: per-feature sum(z), sum(z^2) into stats[256].
// PHASE 1: zhat = z*sc+sh; msg = sigmoid(zh[:64])*softplus(zh[64:]);
//          atomicAdd into au[dst][64].
// ---------------------------------------------------------------------------
template<int PHASE>
__global__ __launch_bounds__(256) void k_edge(
    const void* __restrict__ nbr,
    const int* __restrict__ esrc,
    const int* __restrict__ edst,
    const void* __restrict__ Wv,
    const unsigned short* __restrict__ Pb,   // bf16 bits, [N][256]
    const float* __restrict__ coef,
    float* __restrict__ outAcc,
    long E, const int* __restrict__ flagp)
{
    __shared__ float s_sum[128], s_ss[128];
    const int fp32 = *flagp;
    const int t = threadIdx.x;
    const int wave = t >> 6, lane = t & 63;
    const int n0 = lane & 15, kq = lane >> 4;

    short8 bf[8][2];
    #pragma unroll
    for (int tt = 0; tt < 8; ++tt)
        #pragma unroll
        for (int h = 0; h < 2; ++h)
            #pragma unroll
            for (int jj = 0; jj < 8; ++jj) {
                int k = 128 + h*32 + kq*8 + jj;
                bf[tt][h][jj] = (short)f2bb(ldf(Wv, (long)k*128 + tt*16 + n0, fp32));
            }

    float sc[8], sh[8];
    if (PHASE == 1) {
        #pragma unroll
        for (int tt = 0; tt < 8; ++tt) {
            sc[tt] = coef[tt*16 + n0];
            sh[tt] = coef[128 + tt*16 + n0];
        }
    }
    float lsum[8], lss[8];
    if (PHASE == 0) {
        if (t < 128) { s_sum[t] = 0.f; s_ss[t] = 0.f; }
        #pragma unroll
        for (int tt = 0; tt < 8; ++tt) { lsum[tt] = 0.f; lss[tt] = 0.f; }
    }

    const long nGroups = (E + 15) / 16;
    for (long g = (long)blockIdx.x*4 + wave; g < nGroups; g += (long)gridDim.x*4) {
        long e0 = g * 16;
        long ea = e0 + n0;
        short8 a_lo = {}, a_hi = {};
        if (ea < E) {
            a_lo = loadRow8(nbr, ea*64 + kq*8, fp32);
            a_hi = loadRow8(nbr, ea*64 + 32 + kq*8, fp32);
        }
        floatx4 acc[8];
        #pragma unroll
        for (int tt = 0; tt < 8; ++tt) {
            floatx4 c = {0.f, 0.f, 0.f, 0.f};
            c = __builtin_amdgcn_mfma_f32_16x16x32_bf16(a_lo, bf[tt][0], c, 0, 0, 0);
            c = __builtin_amdgcn_mfma_f32_16x16x32_bf16(a_hi, bf[tt][1], c, 0, 0, 0);
            acc[tt] = c;
        }
        int sE[4], dE[4];
        #pragma unroll
        for (int r = 0; r < 4; ++r) {
            long er = e0 + kq*4 + r;
            sE[r] = (er < E) ? esrc[er] : 0;
            dE[r] = (er < E) ? edst[er] : 0;
        }
        if (PHASE == 0) {
            #pragma unroll
            for (int tt = 0; tt < 8; ++tt) {
                int n = tt*16 + n0;
                #pragma unroll
                for (int r = 0; r < 4; ++r) {
                    long er = e0 + kq*4 + r;
                    if (er < E) {
                        float z = lclamp(acc[tt][r]
                                + bits2f(Pb[(long)sE[r]*256 + n])
                                + bits2f(Pb[(long)dE[r]*256 + 128 + n]));
                        lsum[tt] += z; lss[tt] += z*z;
                    }
                }
            }
        } else {
            float zh[8][4];
            #pragma unroll
            for (int tt = 0; tt < 8; ++tt) {
                int n = tt*16 + n0;
                #pragma unroll
                for (int r = 0; r < 4; ++r) {
                    float z = lclamp(acc[tt][r]
                            + bits2f(Pb[(long)sE[r]*256 + n])
                            + bits2f(Pb[(long)dE[r]*256 + 128 + n]));
                    zh[tt][r] = z * sc[tt] + sh[tt];
                }
            }
            #pragma unroll
            for (int tt = 0; tt < 4; ++tt) {
                #pragma unroll
                for (int r = 0; r < 4; ++r) {
                    long er = e0 + kq*4 + r;
                    if (er < E) {
                        float f = zh[tt][r], c = zh[tt+4][r];
                        float sig = 1.f / (1.f + __expf(-f));
                        float sp  = fmaxf(c, 0.f) + log1pf(__expf(-fabsf(c)));
                        atomicAdd(outAcc + (long)dE[r]*64 + tt*16 + n0, sig * sp);
                    }
                }
            }
        }
    }
    if (PHASE == 0) {
        __syncthreads();
        #pragma unroll
        for (int tt = 0; tt < 8; ++tt) {
            atomicAdd(&s_sum[tt*16 + n0], lsum[tt]);
            atomicAdd(&s_ss[tt*16 + n0], lss[tt]);
        }
        __syncthreads();
        if (t < 128) {
            atomicAdd(&outAcc[t], s_sum[t]);
            atomicAdd(&outAcc[128 + t], s_ss[t]);
        }
    }
}

// ---------------------------------------------------------------------------
__global__ void k_fin1(const float* __restrict__ stats,
                       const void* __restrict__ gamma,
                       const void* __restrict__ beta,
                       float* __restrict__ coef, float invE,
                       const int* __restrict__ flagp)
{
    const int fp32 = *flagp;
    int t = threadIdx.x;  // 128
    float mean = stats[t] * invE;
    float var  = fmaxf(stats[128 + t] * invE - mean * mean, 0.f);
    float sc = ldf(gamma, t, fp32) * rsqrtf(var + 1e-5f);
    coef[t] = sc;
    coef[128 + t] = ldf(beta, t, fp32) - mean * sc;
}

__global__ void k_au_stats(const float* __restrict__ au, float* __restrict__ stats, int N)
{
    __shared__ float s_red[256];
    int t = threadIdx.x;
    int j = t & 63, r = t >> 6;
    float lsum = 0.f, lss = 0.f;
    for (int base = blockIdx.x * 4; base < N; base += gridDim.x * 4) {
        int a = base + r;
        if (a < N) { float v = au[(long)a*64 + j]; lsum += v; lss += v*v; }
    }
    s_red[t] = lsum; __syncthreads();
    if (t < 64) atomicAdd(&stats[j], s_red[j] + s_red[j+64] + s_red[j+128] + s_red[j+192]);
    __syncthreads();
    s_red[t] = lss; __syncthreads();
    if (t < 64) atomicAdd(&stats[64+j], s_red[j] + s_red[j+64] + s_red[j+128] + s_red[j+192]);
}

__global__ void k_fin2(const float* __restrict__ stats,
                       const void* __restrict__ gamma,
                       const void* __restrict__ beta,
                       float* __restrict__ coef, float invN,
                       const int* __restrict__ flagp)
{
    const int fp32 = *flagp;
    int t = threadIdx.x;  // 64
    float mean = stats[t] * invN;
    float var  = fmaxf(stats[64 + t] * invN - mean * mean, 0.f);
    float sc = ldf(gamma, t, fp32) * rsqrtf(var + 1e-5f);
    coef[t] = sc;
    coef[64 + t] = ldf(beta, t, fp32) - mean * sc;
}

__global__ void k_out(const void* __restrict__ atom,
                      const float* __restrict__ au,
                      const float* __restrict__ coef2,
                      void* __restrict__ out, long total,
                      const int* __restrict__ flagp)
{
    const int fp32 = *flagp;
    long i = (long)blockIdx.x * blockDim.x + threadIdx.x;
    if (i >= total) return;
    int j = (int)(i & 63);
    float x = lclamp(ldf(atom, i, fp32) + au[i] * coef2[j] + coef2[64 + j]);
    float sp = fmaxf(x, 0.f) + log1pf(__expf(-fabsf(x)));
    if (fp32) ((float*)out)[i] = sp;
    else      ((__hip_bfloat16*)out)[i] = __float2bfloat16(sp);
}

// ---------------------------------------------------------------------------
extern "C" void kernel_launch(void* const* d_in, const int* in_sizes, int n_in,
                              void* d_out, int out_size, void* d_ws, size_t ws_size,
                              hipStream_t stream)
{
    const void* atom = d_in[0];
    const void* nbr  = d_in[1];
    const int* esrc = (const int*)d_in[2];
    const int* edst = (const int*)d_in[3];
    const void* Wv  = d_in[4];
    const void* bv  = d_in[5];
    const void* g1  = d_in[6];
    const void* be1 = d_in[7];
    const void* g2  = d_in[8];
    const void* be2 = d_in[9];

    const int  N = in_sizes[0] / 64;
    const long E = (long)in_sizes[1] / 64;

    char* w = (char*)d_ws;
    __hip_bfloat16* P = (__hip_bfloat16*)w;  w += (size_t)N * 256 * sizeof(__hip_bfloat16);
    float* au     = (float*)w;               w += (size_t)N * 64 * sizeof(float);
    float* stats1 = (float*)w;               w += 256 * sizeof(float);
    float* stats2 = (float*)w;               w += 128 * sizeof(float);
    float* coef1  = (float*)w;               w += 256 * sizeof(float);
    float* coef2  = (float*)w;               w += 128 * sizeof(float);
    int* flagp    = (int*)w;

    hipMemsetAsync(au, 0, (size_t)N * 64 * sizeof(float), stream);
    hipMemsetAsync(stats1, 0, 384 * sizeof(float), stream);

    k_probe<<<1, 64, 0, stream>>>((const unsigned short*)Wv, flagp);
    k_atom_proj<<<1024, 256, 0, stream>>>(atom, Wv, bv, P, N, flagp);
    k_edge<0><<<2048, 256, 0, stream>>>(nbr, esrc, edst, Wv,
                                        (const unsigned short*)P, nullptr, stats1, E, flagp);
    k_fin1<<<1, 128, 0, stream>>>(stats1, g1, be1, coef1, 1.0f / (float)E, flagp);
    k_edge<1><<<2048, 256, 0, stream>>>(nbr, esrc, edst, Wv,
                                        (const unsigned short*)P, coef1, au, E, flagp);
    k_au_stats<<<1024, 256, 0, stream>>>(au, stats2, N);
    k_fin2<<<1, 64, 0, stream>>>(stats2, g2, be2, coef2, 1.0f / (float)N, flagp);
    long total = (long)N * 64;
    k_out<<<(int)((total + 255) / 256), 256, 0, stream>>>(atom, au, coef2,
                                                          d_out, total, flagp);
}